// Round 4
// baseline (593.916 us; speedup 1.0000x reference)
//
#include <hip/hip_runtime.h>

// ---------- problem constants ----------
#define BB   4096   // batch
#define IN_  256
#define NN   128
#define KK   4
#define JJ   64
#define NG   512        // N*K
#define WS_  131072     // IN*NG
#define PER  131584     // WS_+NG
#define TP   263168     // 2*PER
#define OUTD 128

typedef __attribute__((ext_vector_type(8))) short short8;
typedef __attribute__((ext_vector_type(4))) float f32x4;

__device__ __forceinline__ unsigned short f2bf(float f){
  unsigned u = __float_as_uint(f);
  return (unsigned short)((u + 0x7fffu + ((u >> 16) & 1u)) >> 16);
}

__device__ __forceinline__ void gload16(const void* g, void* l){
  __builtin_amdgcn_global_load_lds((const __attribute__((address_space(1))) void*)g,
                                   (__attribute__((address_space(3))) void*)l, 16, 0, 0);
}

// ---------- 1. f32 -> bf16 convert: x, Wb0, Wb1 ----------
#define XE  (4096u*256u)            // 1048576
#define W0E (XE + 8388608u)         // + 128*4*64*256
#define W1E (W0E + 4194304u)        // + 128*4*64*128

__global__ void k_convert(const float* __restrict__ x,
                          const float* __restrict__ w0,
                          const float* __restrict__ w1,
                          unsigned short* __restrict__ xb,
                          unsigned short* __restrict__ w0b,
                          unsigned short* __restrict__ w1b){
  size_t i = ((size_t)blockIdx.x*256 + threadIdx.x)*4;
  if (i >= W1E) return;
  const float* s; unsigned short* d; size_t off;
  if (i < XE)       { s = x;  d = xb;  off = i; }
  else if (i < W0E) { s = w0; d = w0b; off = i - XE; }
  else              { s = w1; d = w1b; off = i - W0E; }
  float4 v = *(const float4*)(s + off);
  ushort4 o;
  o.x = f2bf(v.x); o.y = f2bf(v.y); o.z = f2bf(v.z); o.w = f2bf(v.w);
  *(ushort4*)(d + off) = o;
}

// ---------- 2. hypernet MLP (context -> hv2[64]) ----------
__global__ void k_hyper(const float* __restrict__ ctx,
                        const float* __restrict__ h1w, const float* __restrict__ h1b,
                        const float* __restrict__ h2w, const float* __restrict__ h2b,
                        float* __restrict__ hv2){
  __shared__ float s1[32];
  int t = threadIdx.x;
  if (t < 32){
    float a = h1b[t];
    #pragma unroll 8
    for (int i = 0; i < 64; ++i) a += ctx[i]*h1w[t*64+i];
    s1[t] = fmaxf(a, 0.f);
  }
  __syncthreads();
  float a = h2b[t];
  #pragma unroll 8
  for (int i = 0; i < 32; ++i) a += s1[i]*h2w[t*32+i];
  hv2[t] = fmaxf(a, 0.f);
}

// ---------- 3. gw = hv2 @ h3w.T + h3b  ->  Wg_bf (1024x256 bf16), bg (1024 f32) ----------
__global__ void k_gw(const float* __restrict__ hv2,
                     const float* __restrict__ h3w, const float* __restrict__ h3b,
                     unsigned short* __restrict__ Wg_bf, float* __restrict__ bg){
  int t = threadIdx.x;
  int r = blockIdx.x*64 + (t >> 2);
  int q = t & 3;
  const float4* row = (const float4*)(h3w + (size_t)r*64);
  float a = 0.f;
  #pragma unroll
  for (int i = 0; i < 4; ++i){
    float4 v = row[q*4 + i];
    float4 h = *(const float4*)(hv2 + q*16 + i*4);
    a += v.x*h.x + v.y*h.y + v.z*h.z + v.w*h.w;
  }
  a += __shfl_xor(a, 1);
  a += __shfl_xor(a, 2);
  if (q == 0){
    a += h3b[r];
    if (r < WS_)          Wg_bf[r] = f2bf(a);
    else if (r < PER)     bg[r - WS_] = a;
    else if (r < PER+WS_) Wg_bf[WS_ + (r - PER)] = f2bf(a);
    else                  bg[512 + (r - (PER+WS_))] = a;
  }
}

// ---------- 4. gates GEMM: G_T[m(1024)][b(4096)] = sigmoid(Wg[m]·x[b] + bg[m]) ----------
__global__ __launch_bounds__(512, 1)
void k_gates(const unsigned short* __restrict__ Wg_bf,  // 1024 x 256
             const unsigned short* __restrict__ x_bf,   // 4096 x 256
             const float* __restrict__ bg,              // 1024
             float* __restrict__ GT){                    // 1024 x 4096
  __shared__ __align__(16) unsigned short As[128*64];
  __shared__ __align__(16) unsigned short Bs[256*64];
  const int tid  = threadIdx.x;
  const int lane = tid & 63;
  const int wid  = tid >> 6;
  const int wm = wid >> 2, wn = wid & 3;
  const int lrow = lane & 15, lk = lane >> 4;
  const int m0 = blockIdx.x*128;
  const int b0 = blockIdx.y*256;

  f32x4 zero = {0.f,0.f,0.f,0.f};
  f32x4 acc[4][4];
  #pragma unroll
  for (int i=0;i<4;++i)
    #pragma unroll
    for (int j=0;j<4;++j) acc[i][j] = zero;

  for (int kt = 0; kt < 256/64; ++kt){
    __syncthreads();
    #pragma unroll
    for (int i = 0; i < 2; ++i){
      int c = tid + i*512;
      int row = c >> 3, k8 = c & 7;
      uint4 v = *(const uint4*)(Wg_bf + (size_t)(m0+row)*256 + kt*64 + k8*8);
      int idx = (row*64 + k8*8) ^ ((row & 7) << 3);
      *(uint4*)(&As[idx]) = v;
    }
    #pragma unroll
    for (int i = 0; i < 4; ++i){
      int c = tid + i*512;
      int row = c >> 3, k8 = c & 7;
      uint4 v = *(const uint4*)(x_bf + (size_t)(b0+row)*256 + kt*64 + k8*8);
      int idx = (row*64 + k8*8) ^ ((row & 7) << 3);
      *(uint4*)(&Bs[idx]) = v;
    }
    __syncthreads();
    #pragma unroll
    for (int kk = 0; kk < 2; ++kk){
      short8 a[4], b[4];
      #pragma unroll
      for (int fm = 0; fm < 4; ++fm){
        int m = wm*64 + fm*16 + lrow;
        int idx = (m*64 + kk*32 + lk*8) ^ ((m & 7) << 3);
        a[fm] = *(const short8*)(&As[idx]);
      }
      #pragma unroll
      for (int fn = 0; fn < 4; ++fn){
        int r = wn*64 + fn*16 + lrow;
        int idx = (r*64 + kk*32 + lk*8) ^ ((r & 7) << 3);
        b[fn] = *(const short8*)(&Bs[idx]);
      }
      #pragma unroll
      for (int fm = 0; fm < 4; ++fm)
        #pragma unroll
        for (int fn = 0; fn < 4; ++fn)
          acc[fm][fn] = __builtin_amdgcn_mfma_f32_16x16x32_bf16(a[fm], b[fn], acc[fm][fn], 0, 0, 0);
    }
  }
  #pragma unroll
  for (int fm = 0; fm < 4; ++fm){
    float4 bgv = *(const float4*)(bg + m0 + wm*64 + fm*16 + lk*4);
    float bga[4] = {bgv.x, bgv.y, bgv.z, bgv.w};
    #pragma unroll
    for (int reg = 0; reg < 4; ++reg){
      int m = m0 + wm*64 + fm*16 + lk*4 + reg;
      #pragma unroll
      for (int fn = 0; fn < 4; ++fn){
        int b = b0 + wn*64 + fn*16 + lrow;
        float z = acc[fm][fn][reg] + bga[reg];
        GT[(size_t)m*4096 + b] = 1.f/(1.f + __expf(-z));
      }
    }
  }
}

// ---------- 5/6. fused DANN layer (A direct-to-reg, B-only LDS, 2 blocks/CU) ----------
// out[b,n] = sum_{k,j} relu(A[b]·Wb[n,k,j] + bb[n,k,j]) * gate[b,n,k] * Ws[n,k*64+j] + bs[n]
// grid 512 = 8 XCD x (32 bgroups x 2 n-halves). LDS: B dbuf 64KB + part 2KB
// -> 2 blocks/CU; __launch_bounds__(512,4) caps regs at 128 (16 waves/CU).
// A fragments load global->VGPR (x slice L1/L2-resident, reused 4x across wn).
// Counted vmcnt: region = 8 A-loads + 4 B-stage -> vmcnt(12) drains prev tile.
template<int KIN, int LAYER>
__global__ __launch_bounds__(512, 4)
void k_layer(const unsigned short* __restrict__ Abf,  // (4096, KIN) bf16
             const unsigned short* __restrict__ Wbf,  // (32768, KIN) bf16
             const float* __restrict__ bb,            // 32768
             const float* __restrict__ Ws,            // 128*256
             const float* __restrict__ bs,            // 128
             const float* __restrict__ GT,            // 1024 x 4096
             unsigned short* __restrict__ cur_bf,     // layer0 out (bf16, 4096x128)
             float* __restrict__ out1){               // layer1 out (f32, 4096x128)
  constexpr int NT = KIN/64;
  __shared__ __align__(16) unsigned short Bs[2][16384];  // B dbuf 256x64
  __shared__ float part[4][128];

  const int tid  = threadIdx.x;
  const int lane = tid & 63;
  const int wid  = tid >> 6;
  const int wm = wid >> 2, wn = wid & 3;
  const int lrow = lane & 15, lk = lane >> 4;

  const int id     = blockIdx.x;
  const int xcd    = id & 7;
  const int j      = id >> 3;                 // 0..63
  const int nstart = xcd*16 + (j & 1)*8;      // XCD-affine 8-n slice
  const int bbase  = (j >> 1) << 7;           // 32 bgroups * 128

  f32x4 zero = {0.f,0.f,0.f,0.f};
  f32x4 acc[4][4];
  #pragma unroll
  for (int i=0;i<4;++i)
    #pragma unroll
    for (int jj=0;jj<4;++jj) acc[i][jj] = zero;

  // per-lane A row base (rows bbase + wm*64 + fm*16 + lrow)
  const unsigned short* arow = Abf + (size_t)(bbase + wm*64 + lrow)*KIN + lk*8;

  // B-tile stage: 256x64 = 2048 16B chunks; linear LDS dest, pre-swizzled src.
  auto STAGE_B = [&](int buf, int n, int kt){
    #pragma unroll
    for (int i = 0; i < 4; ++i){
      int c = i*512 + tid;
      int row = c >> 3, kc = c & 7;
      const unsigned short* s = Wbf + (size_t)((n<<8)+row)*KIN + kt*64 + ((kc ^ (row&7))<<3);
      gload16(s, &Bs[buf][(i*512 + wid*64)*8]);
    }
  };

  STAGE_B(0, nstart, 0);
  asm volatile("" ::: "memory");   // pin: prologue stage precedes loop VMEM

  int buf = 0;
  #pragma unroll 1
  for (int nn = 0; nn < 8; ++nn){
    const int n = nstart + nn;
    #pragma unroll
    for (int kt = 0; kt < NT; ++kt){
      const bool epi  = (kt == NT-1);
      const bool last = epi && (nn == 7);

      // A fragments: global -> VGPR (8 x dwordx4, counted in vmcnt)
      short8 a[2][4];
      #pragma unroll
      for (int kk = 0; kk < 2; ++kk)
        #pragma unroll
        for (int fm = 0; fm < 4; ++fm)
          a[kk][fm] = *(const short8*)(arow + (size_t)fm*16*KIN + kt*64 + kk*32);

      if (!last){
        int nb = n, nkt = kt + 1;
        if (nkt == NT){ nkt = 0; nb = n + 1; }
        STAGE_B(buf ^ 1, nb, nkt);
      }
      // drain previous B-tile's 4 stage ops (oldest): region issued 8 A (+4 B)
      if (last) asm volatile("s_waitcnt vmcnt(8)" ::: "memory");
      else      asm volatile("s_waitcnt vmcnt(12)" ::: "memory");
      __builtin_amdgcn_s_barrier();

      #pragma unroll
      for (int kk = 0; kk < 2; ++kk){
        short8 b[4];
        #pragma unroll
        for (int fn = 0; fn < 4; ++fn){
          int r = wn*64 + fn*16 + lrow;
          int idx = (r*64 + kk*32 + lk*8) ^ ((r & 7) << 3);
          b[fn] = *(const short8*)(&Bs[buf][idx]);
        }
        #pragma unroll
        for (int fm = 0; fm < 4; ++fm)
          #pragma unroll
          for (int fn = 0; fn < 4; ++fn)
            acc[fm][fn] = __builtin_amdgcn_mfma_f32_16x16x32_bf16(a[kk][fm], b[fn], acc[fm][fn], 0, 0, 0);
      }

      if (epi){
        // gate/bias/scale loads after MFMAs (keeps them out of the reg peak)
        const int gidx = LAYER*512 + n*4 + wn;      // wn == k
        float bbv[4], wsv[4];
        #pragma unroll
        for (int fn = 0; fn < 4; ++fn){
          int c = wn*64 + fn*16 + lrow;
          bbv[fn] = bb[n*256 + c];
          wsv[fn] = Ws[n*256 + c];
        }
        #pragma unroll
        for (int fm = 0; fm < 4; ++fm){
          float4 g = *(const float4*)(GT + (size_t)gidx*4096 + bbase + wm*64 + fm*16 + lk*4);
          float gr[4] = {g.x, g.y, g.z, g.w};
          #pragma unroll
          for (int reg = 0; reg < 4; ++reg){
            float sum = 0.f;
            #pragma unroll
            for (int fn = 0; fn < 4; ++fn)
              sum += fmaxf(acc[fm][fn][reg] + bbv[fn], 0.f) * wsv[fn];
            sum *= gr[reg];
            sum += __shfl_xor(sum, 1);
            sum += __shfl_xor(sum, 2);
            sum += __shfl_xor(sum, 4);
            sum += __shfl_xor(sum, 8);
            if (lrow == 0) part[wn][wm*64 + fm*16 + lk*4 + reg] = sum;
          }
        }
        asm volatile("s_waitcnt lgkmcnt(0)" ::: "memory");
        __builtin_amdgcn_s_barrier();
        if (tid < 128){
          float v = part[0][tid] + part[1][tid] + part[2][tid] + part[3][tid] + bs[n];
          if (LAYER == 0) cur_bf[(size_t)(bbase+tid)*128 + n] = f2bf(v);
          else            out1[(size_t)(bbase+tid)*128 + n] = v;
        }
        #pragma unroll
        for (int i2 = 0; i2 < 4; ++i2)
          #pragma unroll
          for (int j2 = 0; j2 < 4; ++j2) acc[i2][j2] = zero;
      } else {
        __builtin_amdgcn_s_barrier();
      }
      buf ^= 1;
    }
  }
}

// ---------- 7. final projection: out = cur1 @ Wout.T + bout ----------
__global__ void k_final(const float* __restrict__ out1, const float* __restrict__ Wout,
                        const float* __restrict__ bout, float* __restrict__ out){
  int t = blockIdx.x*256 + threadIdx.x;
  int b = t >> 7, o = t & 127;
  const float4* cr = (const float4*)(out1 + (size_t)b*128);
  const float4* wr = (const float4*)(Wout + (size_t)o*128);
  float a = 0.f;
  #pragma unroll
  for (int i = 0; i < 32; ++i){
    float4 c = cr[i], w = wr[i];
    a += c.x*w.x + c.y*w.y + c.z*w.z + c.w*w.w;
  }
  out[t] = a + bout[o];
}

// ---------- launch ----------
extern "C" void kernel_launch(void* const* d_in, const int* in_sizes, int n_in,
                              void* d_out, int out_size, void* d_ws, size_t ws_size,
                              hipStream_t stream){
  const float* x    = (const float*)d_in[0];
  const float* ctx  = (const float*)d_in[1];
  const float* Wb0  = (const float*)d_in[2];
  const float* bb0  = (const float*)d_in[3];
  const float* Ws0  = (const float*)d_in[4];
  const float* bs0  = (const float*)d_in[5];
  const float* Wb1  = (const float*)d_in[6];
  const float* bb1  = (const float*)d_in[7];
  const float* Ws1  = (const float*)d_in[8];
  const float* bs1  = (const float*)d_in[9];
  const float* Wout = (const float*)d_in[10];
  const float* bout = (const float*)d_in[11];
  const float* h1w  = (const float*)d_in[12];
  const float* h1b  = (const float*)d_in[13];
  const float* h2w  = (const float*)d_in[14];
  const float* h2b  = (const float*)d_in[15];
  const float* h3w  = (const float*)d_in[16];
  const float* h3b  = (const float*)d_in[17];
  float* out = (float*)d_out;

  char* ws = (char*)d_ws;
  size_t o = 0;
  unsigned short* x_bf  = (unsigned short*)(ws + o); o += (size_t)4096*256*2;
  unsigned short* W0b   = (unsigned short*)(ws + o); o += (size_t)8388608*2;
  unsigned short* W1b   = (unsigned short*)(ws + o); o += (size_t)4194304*2;
  unsigned short* Wg_bf = (unsigned short*)(ws + o); o += (size_t)1024*256*2;
  float* bg   = (float*)(ws + o); o += 1024*4;
  float* hv2  = (float*)(ws + o); o += 256;
  float* GT   = (float*)(ws + o); o += (size_t)1024*4096*4;
  unsigned short* cur_bf = (unsigned short*)(ws + o); o += (size_t)4096*128*2;
  float* out1 = (float*)(ws + o); o += (size_t)4096*128*4;

  k_convert<<<13312, 256, 0, stream>>>(x, Wb0, Wb1, x_bf, W0b, W1b);
  k_hyper<<<1, 64, 0, stream>>>(ctx, h1w, h1b, h2w, h2b, hv2);
  k_gw<<<4112, 256, 0, stream>>>(hv2, h3w, h3b, Wg_bf, bg);
  k_gates<<<dim3(8, 16), 512, 0, stream>>>(Wg_bf, x_bf, bg, GT);
  k_layer<256, 0><<<512, 512, 0, stream>>>(x_bf, W0b, bb0, Ws0, bs0, GT, cur_bf, out1);
  k_layer<128, 1><<<512, 512, 0, stream>>>(cur_bf, W1b, bb1, Ws1, bs1, GT, cur_bf, out1);
  k_final<<<2048, 256, 0, stream>>>(out1, Wout, bout, out);
}

// Round 5
// 358.127 us; speedup vs baseline: 1.6584x; 1.6584x over previous
//
#include <hip/hip_runtime.h>

// ---------- problem constants ----------
#define BB   4096   // batch
#define IN_  256
#define NN   128
#define KK   4
#define JJ   64
#define NG   512        // N*K
#define WS_  131072     // IN*NG
#define PER  131584     // WS_+NG
#define TP   263168     // 2*PER
#define OUTD 128

typedef __attribute__((ext_vector_type(8))) short short8;
typedef __attribute__((ext_vector_type(4))) float f32x4;

__device__ __forceinline__ unsigned short f2bf(float f){
  unsigned u = __float_as_uint(f);
  return (unsigned short)((u + 0x7fffu + ((u >> 16) & 1u)) >> 16);
}

__device__ __forceinline__ void gload16(const void* g, void* l){
  __builtin_amdgcn_global_load_lds((const __attribute__((address_space(1))) void*)g,
                                   (__attribute__((address_space(3))) void*)l, 16, 0, 0);
}

// ---------- 1. f32 -> bf16 convert: x, Wb0, Wb1 ----------
#define XE  (4096u*256u)            // 1048576
#define W0E (XE + 8388608u)         // + 128*4*64*256
#define W1E (W0E + 4194304u)        // + 128*4*64*128

__global__ void k_convert(const float* __restrict__ x,
                          const float* __restrict__ w0,
                          const float* __restrict__ w1,
                          unsigned short* __restrict__ xb,
                          unsigned short* __restrict__ w0b,
                          unsigned short* __restrict__ w1b){
  size_t i = ((size_t)blockIdx.x*256 + threadIdx.x)*4;
  if (i >= W1E) return;
  const float* s; unsigned short* d; size_t off;
  if (i < XE)       { s = x;  d = xb;  off = i; }
  else if (i < W0E) { s = w0; d = w0b; off = i - XE; }
  else              { s = w1; d = w1b; off = i - W0E; }
  float4 v = *(const float4*)(s + off);
  ushort4 o;
  o.x = f2bf(v.x); o.y = f2bf(v.y); o.z = f2bf(v.z); o.w = f2bf(v.w);
  *(ushort4*)(d + off) = o;
}

// ---------- 2. hypernet MLP (context -> hv2[64]) ----------
__global__ void k_hyper(const float* __restrict__ ctx,
                        const float* __restrict__ h1w, const float* __restrict__ h1b,
                        const float* __restrict__ h2w, const float* __restrict__ h2b,
                        float* __restrict__ hv2){
  __shared__ float s1[32];
  int t = threadIdx.x;
  if (t < 32){
    float a = h1b[t];
    #pragma unroll 8
    for (int i = 0; i < 64; ++i) a += ctx[i]*h1w[t*64+i];
    s1[t] = fmaxf(a, 0.f);
  }
  __syncthreads();
  float a = h2b[t];
  #pragma unroll 8
  for (int i = 0; i < 32; ++i) a += s1[i]*h2w[t*32+i];
  hv2[t] = fmaxf(a, 0.f);
}

// ---------- 3. gw = hv2 @ h3w.T + h3b  ->  Wg_bf (1024x256 bf16), bg (1024 f32) ----------
__global__ void k_gw(const float* __restrict__ hv2,
                     const float* __restrict__ h3w, const float* __restrict__ h3b,
                     unsigned short* __restrict__ Wg_bf, float* __restrict__ bg){
  int t = threadIdx.x;
  int r = blockIdx.x*64 + (t >> 2);
  int q = t & 3;
  const float4* row = (const float4*)(h3w + (size_t)r*64);
  float a = 0.f;
  #pragma unroll
  for (int i = 0; i < 4; ++i){
    float4 v = row[q*4 + i];
    float4 h = *(const float4*)(hv2 + q*16 + i*4);
    a += v.x*h.x + v.y*h.y + v.z*h.z + v.w*h.w;
  }
  a += __shfl_xor(a, 1);
  a += __shfl_xor(a, 2);
  if (q == 0){
    a += h3b[r];
    if (r < WS_)          Wg_bf[r] = f2bf(a);
    else if (r < PER)     bg[r - WS_] = a;
    else if (r < PER+WS_) Wg_bf[WS_ + (r - PER)] = f2bf(a);
    else                  bg[512 + (r - (PER+WS_))] = a;
  }
}

// ---------- 4. gates GEMM: G_T[m(1024)][b(4096)] = sigmoid(Wg[m]·x[b] + bg[m]) ----------
__global__ __launch_bounds__(512, 1)
void k_gates(const unsigned short* __restrict__ Wg_bf,  // 1024 x 256
             const unsigned short* __restrict__ x_bf,   // 4096 x 256
             const float* __restrict__ bg,              // 1024
             float* __restrict__ GT){                    // 1024 x 4096
  __shared__ __align__(16) unsigned short As[128*64];
  __shared__ __align__(16) unsigned short Bs[256*64];
  const int tid  = threadIdx.x;
  const int lane = tid & 63;
  const int wid  = tid >> 6;
  const int wm = wid >> 2, wn = wid & 3;
  const int lrow = lane & 15, lk = lane >> 4;
  const int m0 = blockIdx.x*128;
  const int b0 = blockIdx.y*256;

  f32x4 zero = {0.f,0.f,0.f,0.f};
  f32x4 acc[4][4];
  #pragma unroll
  for (int i=0;i<4;++i)
    #pragma unroll
    for (int j=0;j<4;++j) acc[i][j] = zero;

  for (int kt = 0; kt < 256/64; ++kt){
    __syncthreads();
    #pragma unroll
    for (int i = 0; i < 2; ++i){
      int c = tid + i*512;
      int row = c >> 3, k8 = c & 7;
      uint4 v = *(const uint4*)(Wg_bf + (size_t)(m0+row)*256 + kt*64 + k8*8);
      int idx = (row*64 + k8*8) ^ ((row & 7) << 3);
      *(uint4*)(&As[idx]) = v;
    }
    #pragma unroll
    for (int i = 0; i < 4; ++i){
      int c = tid + i*512;
      int row = c >> 3, k8 = c & 7;
      uint4 v = *(const uint4*)(x_bf + (size_t)(b0+row)*256 + kt*64 + k8*8);
      int idx = (row*64 + k8*8) ^ ((row & 7) << 3);
      *(uint4*)(&Bs[idx]) = v;
    }
    __syncthreads();
    #pragma unroll
    for (int kk = 0; kk < 2; ++kk){
      short8 a[4], b[4];
      #pragma unroll
      for (int fm = 0; fm < 4; ++fm){
        int m = wm*64 + fm*16 + lrow;
        int idx = (m*64 + kk*32 + lk*8) ^ ((m & 7) << 3);
        a[fm] = *(const short8*)(&As[idx]);
      }
      #pragma unroll
      for (int fn = 0; fn < 4; ++fn){
        int r = wn*64 + fn*16 + lrow;
        int idx = (r*64 + kk*32 + lk*8) ^ ((r & 7) << 3);
        b[fn] = *(const short8*)(&Bs[idx]);
      }
      #pragma unroll
      for (int fm = 0; fm < 4; ++fm)
        #pragma unroll
        for (int fn = 0; fn < 4; ++fn)
          acc[fm][fn] = __builtin_amdgcn_mfma_f32_16x16x32_bf16(a[fm], b[fn], acc[fm][fn], 0, 0, 0);
    }
  }
  #pragma unroll
  for (int fm = 0; fm < 4; ++fm){
    float4 bgv = *(const float4*)(bg + m0 + wm*64 + fm*16 + lk*4);
    float bga[4] = {bgv.x, bgv.y, bgv.z, bgv.w};
    #pragma unroll
    for (int reg = 0; reg < 4; ++reg){
      int m = m0 + wm*64 + fm*16 + lk*4 + reg;
      #pragma unroll
      for (int fn = 0; fn < 4; ++fn){
        int b = b0 + wn*64 + fn*16 + lrow;
        float z = acc[fm][fn][reg] + bga[reg];
        GT[(size_t)m*4096 + b] = 1.f/(1.f + __expf(-z));
      }
    }
  }
}

// ---------- 5/6. fused DANN layer ----------
// A-operand direct global->VGPR (L1/L2-served; kills the 4x wn-redundant A
// LDS reads). B (Wb) in LDS, TRIPLE-buffered, 2-deep prefetch with counted
// vmcnt: per iter issue = 8 A-loads + 4 B-stage (in that order).
//   drain stage_for(gi): younger ops = gi==0 -> 12; steady -> 20; last -> 8.
// One publish barrier per iter; buffer overwrite safe because stage_for(t+2)
// is issued only after the barrier all waves cross post-(t-1)-reads.
// grid 256 = 8 xcd x 32 bgroup, lockstep nn=0..15 (round-3 proven L2 reuse).
template<int KIN, int LAYER>
__global__ __launch_bounds__(512, 2)
void k_layer(const unsigned short* __restrict__ Abf,  // (4096, KIN) bf16
             const unsigned short* __restrict__ Wbf,  // (32768, KIN) bf16
             const float* __restrict__ bb,            // 32768
             const float* __restrict__ Ws,            // 128*256
             const float* __restrict__ bs,            // 128
             const float* __restrict__ GT,            // 1024 x 4096
             unsigned short* __restrict__ cur_bf,     // layer0 out (bf16, 4096x128)
             float* __restrict__ out1){               // layer1 out (f32, 4096x128)
  constexpr int NT  = KIN/64;
  constexpr int TOT = 16*NT;
  __shared__ __align__(16) unsigned short Bs[3][16384];  // B 3-buf 256x64
  __shared__ float part[4][128];

  const int tid  = threadIdx.x;
  const int lane = tid & 63;
  const int wid  = tid >> 6;
  const int wm = wid >> 2, wn = wid & 3;
  const int lrow = lane & 15, lk = lane >> 4;

  const int id     = blockIdx.x;
  const int nstart = (id & 7) * 16;          // XCD-affine 16-n slice
  const int bbase  = (id >> 3) << 7;         // 32 bgroups * 128

  f32x4 zero = {0.f,0.f,0.f,0.f};
  f32x4 acc[4][4];
  #pragma unroll
  for (int i=0;i<4;++i)
    #pragma unroll
    for (int jj=0;jj<4;++jj) acc[i][jj] = zero;

  // per-lane A row base (rows bbase + wm*64 + fm*16 + lrow)
  const unsigned short* arow = Abf + (size_t)(bbase + wm*64 + lrow)*KIN + lk*8;

  // B-tile stage: 256x64 = 2048 16B chunks; linear LDS dest, pre-swizzled src.
  auto STAGE_B = [&](int buf, int n, int kt){
    #pragma unroll
    for (int i = 0; i < 4; ++i){
      int c = i*512 + tid;
      int row = c >> 3, kc = c & 7;
      const unsigned short* s = Wbf + (size_t)((n<<8)+row)*KIN + kt*64 + ((kc ^ (row&7))<<3);
      gload16(s, &Bs[buf][(i*512 + wid*64)*8]);
    }
  };

  // prologue: stage gi=0 (buf0) and gi=1 (buf1)
  STAGE_B(0, nstart, 0);
  STAGE_B(1, nstart + 1/NT, 1%NT);
  asm volatile("" ::: "memory");   // pin: prologue stages precede loop VMEM

  int cbuf = 0;                     // compute buffer = gi%3
  int sbuf = 2;                     // stage target  = (gi+2)%3
  #pragma unroll 1
  for (int nn = 0; nn < 16; ++nn){
    const int n = nstart + nn;
    #pragma unroll
    for (int kt = 0; kt < NT; ++kt){
      const int  gi  = nn*NT + kt;
      const bool epi = (kt == NT-1);

      // A fragments: global -> VGPR (exactly 8 b128 loads; L1-served)
      short8 a[2][4];
      #pragma unroll
      for (int kk = 0; kk < 2; ++kk)
        #pragma unroll
        for (int fm = 0; fm < 4; ++fm)
          a[kk][fm] = *(const short8*)(arow + (size_t)fm*16*KIN + kt*64 + kk*32);

      // counted drain of stage_for(gi) (issued at gi-2, or prologue)
      if (gi == 0)          asm volatile("s_waitcnt vmcnt(12)" ::: "memory");
      else if (gi == TOT-1) asm volatile("s_waitcnt vmcnt(8)"  ::: "memory");
      else                  asm volatile("s_waitcnt vmcnt(20)" ::: "memory");
      __builtin_amdgcn_s_barrier();           // publish Bs[cbuf]

      // prefetch gi+2
      if (gi + 2 < TOT){
        int g2 = gi + 2;
        STAGE_B(sbuf, nstart + g2/NT, g2 % NT);
      }

      // MFMA phase on Bs[cbuf]
      #pragma unroll
      for (int kk = 0; kk < 2; ++kk){
        short8 b[4];
        #pragma unroll
        for (int fn = 0; fn < 4; ++fn){
          int r = wn*64 + fn*16 + lrow;
          int idx = (r*64 + kk*32 + lk*8) ^ ((r & 7) << 3);
          b[fn] = *(const short8*)(&Bs[cbuf][idx]);
        }
        #pragma unroll
        for (int fm = 0; fm < 4; ++fm)
          #pragma unroll
          for (int fn = 0; fn < 4; ++fn)
            acc[fm][fn] = __builtin_amdgcn_mfma_f32_16x16x32_bf16(a[kk][fm], b[fn], acc[fm][fn], 0, 0, 0);
      }

      if (epi){
        // gate/bias/scale loads after MFMAs; relu*Ws, gate, 16-lane reduce
        const int gidx = LAYER*512 + n*4 + wn;      // wn == k
        float bbv[4], wsv[4];
        #pragma unroll
        for (int fn = 0; fn < 4; ++fn){
          int c = wn*64 + fn*16 + lrow;
          bbv[fn] = bb[n*256 + c];
          wsv[fn] = Ws[n*256 + c];
        }
        #pragma unroll
        for (int fm = 0; fm < 4; ++fm){
          float4 g = *(const float4*)(GT + (size_t)gidx*4096 + bbase + wm*64 + fm*16 + lk*4);
          float gr[4] = {g.x, g.y, g.z, g.w};
          #pragma unroll
          for (int reg = 0; reg < 4; ++reg){
            float sum = 0.f;
            #pragma unroll
            for (int fn = 0; fn < 4; ++fn)
              sum += fmaxf(acc[fm][fn][reg] + bbv[fn], 0.f) * wsv[fn];
            sum *= gr[reg];
            sum += __shfl_xor(sum, 1);
            sum += __shfl_xor(sum, 2);
            sum += __shfl_xor(sum, 4);
            sum += __shfl_xor(sum, 8);
            if (lrow == 0) part[wn][wm*64 + fm*16 + lk*4 + reg] = sum;
          }
        }
        asm volatile("s_waitcnt lgkmcnt(0)" ::: "memory");
        __builtin_amdgcn_s_barrier();
        if (tid < 128){
          float v = part[0][tid] + part[1][tid] + part[2][tid] + part[3][tid] + bs[n];
          if (LAYER == 0) cur_bf[(size_t)(bbase+tid)*128 + n] = f2bf(v);
          else            out1[(size_t)(bbase+tid)*128 + n] = v;
        }
        #pragma unroll
        for (int i2 = 0; i2 < 4; ++i2)
          #pragma unroll
          for (int j2 = 0; j2 < 4; ++j2) acc[i2][j2] = zero;
      }
      cbuf = (cbuf == 2) ? 0 : cbuf + 1;
      sbuf = (sbuf == 2) ? 0 : sbuf + 1;
    }
  }
}

// ---------- 7. final projection: out = cur1 @ Wout.T + bout ----------
__global__ void k_final(const float* __restrict__ out1, const float* __restrict__ Wout,
                        const float* __restrict__ bout, float* __restrict__ out){
  int t = blockIdx.x*256 + threadIdx.x;
  int b = t >> 7, o = t & 127;
  const float4* cr = (const float4*)(out1 + (size_t)b*128);
  const float4* wr = (const float4*)(Wout + (size_t)o*128);
  float a = 0.f;
  #pragma unroll
  for (int i = 0; i < 32; ++i){
    float4 c = cr[i], w = wr[i];
    a += c.x*w.x + c.y*w.y + c.z*w.z + c.w*w.w;
  }
  out[t] = a + bout[o];
}

// ---------- launch ----------
extern "C" void kernel_launch(void* const* d_in, const int* in_sizes, int n_in,
                              void* d_out, int out_size, void* d_ws, size_t ws_size,
                              hipStream_t stream){
  const float* x    = (const float*)d_in[0];
  const float* ctx  = (const float*)d_in[1];
  const float* Wb0  = (const float*)d_in[2];
  const float* bb0  = (const float*)d_in[3];
  const float* Ws0  = (const float*)d_in[4];
  const float* bs0  = (const float*)d_in[5];
  const float* Wb1  = (const float*)d_in[6];
  const float* bb1  = (const float*)d_in[7];
  const float* Ws1  = (const float*)d_in[8];
  const float* bs1  = (const float*)d_in[9];
  const float* Wout = (const float*)d_in[10];
  const float* bout = (const float*)d_in[11];
  const float* h1w  = (const float*)d_in[12];
  const float* h1b  = (const float*)d_in[13];
  const float* h2w  = (const float*)d_in[14];
  const float* h2b  = (const float*)d_in[15];
  const float* h3w  = (const float*)d_in[16];
  const float* h3b  = (const float*)d_in[17];
  float* out = (float*)d_out;

  char* ws = (char*)d_ws;
  size_t o = 0;
  unsigned short* x_bf  = (unsigned short*)(ws + o); o += (size_t)4096*256*2;
  unsigned short* W0b   = (unsigned short*)(ws + o); o += (size_t)8388608*2;
  unsigned short* W1b   = (unsigned short*)(ws + o); o += (size_t)4194304*2;
  unsigned short* Wg_bf = (unsigned short*)(ws + o); o += (size_t)1024*256*2;
  float* bg   = (float*)(ws + o); o += 1024*4;
  float* hv2  = (float*)(ws + o); o += 256;
  float* GT   = (float*)(ws + o); o += (size_t)1024*4096*4;
  unsigned short* cur_bf = (unsigned short*)(ws + o); o += (size_t)4096*128*2;
  float* out1 = (float*)(ws + o); o += (size_t)4096*128*4;

  k_convert<<<13312, 256, 0, stream>>>(x, Wb0, Wb1, x_bf, W0b, W1b);
  k_hyper<<<1, 64, 0, stream>>>(ctx, h1w, h1b, h2w, h2b, hv2);
  k_gw<<<4112, 256, 0, stream>>>(hv2, h3w, h3b, Wg_bf, bg);
  k_gates<<<dim3(8, 16), 512, 0, stream>>>(Wg_bf, x_bf, bg, GT);
  k_layer<256, 0><<<256, 512, 0, stream>>>(x_bf, W0b, bb0, Ws0, bs0, GT, cur_bf, out1);
  k_layer<128, 1><<<256, 512, 0, stream>>>(cur_bf, W1b, bb1, Ws1, bs1, GT, cur_bf, out1);
  k_final<<<2048, 256, 0, stream>>>(out1, Wout, bout, out);
}

// Round 6
// 236.905 us; speedup vs baseline: 2.5070x; 1.5117x over previous
//
#include <hip/hip_runtime.h>

// ---------- problem constants ----------
#define BB   4096   // batch
#define IN_  256
#define NN   128
#define KK   4
#define JJ   64
#define NG   512        // N*K
#define WS_  131072     // IN*NG
#define PER  131584     // WS_+NG
#define TP   263168     // 2*PER
#define OUTD 128

typedef __attribute__((ext_vector_type(8))) short short8;
typedef __attribute__((ext_vector_type(4))) float f32x4;

__device__ __forceinline__ unsigned short f2bf(float f){
  unsigned u = __float_as_uint(f);
  return (unsigned short)((u + 0x7fffu + ((u >> 16) & 1u)) >> 16);
}

__device__ __forceinline__ void gload16(const void* g, void* l){
  __builtin_amdgcn_global_load_lds((const __attribute__((address_space(1))) void*)g,
                                   (__attribute__((address_space(3))) void*)l, 16, 0, 0);
}

// ---------- 1. f32 -> bf16 convert: x, Wb0, Wb1 ----------
#define XE  (4096u*256u)            // 1048576
#define W0E (XE + 8388608u)         // + 128*4*64*256
#define W1E (W0E + 4194304u)        // + 128*4*64*128

__global__ void k_convert(const float* __restrict__ x,
                          const float* __restrict__ w0,
                          const float* __restrict__ w1,
                          unsigned short* __restrict__ xb,
                          unsigned short* __restrict__ w0b,
                          unsigned short* __restrict__ w1b){
  size_t i = ((size_t)blockIdx.x*256 + threadIdx.x)*4;
  if (i >= W1E) return;
  const float* s; unsigned short* d; size_t off;
  if (i < XE)       { s = x;  d = xb;  off = i; }
  else if (i < W0E) { s = w0; d = w0b; off = i - XE; }
  else              { s = w1; d = w1b; off = i - W0E; }
  float4 v = *(const float4*)(s + off);
  ushort4 o;
  o.x = f2bf(v.x); o.y = f2bf(v.y); o.z = f2bf(v.z); o.w = f2bf(v.w);
  *(ushort4*)(d + off) = o;
}

// ---------- 2. hypernet MLP (context -> hv2[64]) ----------
__global__ void k_hyper(const float* __restrict__ ctx,
                        const float* __restrict__ h1w, const float* __restrict__ h1b,
                        const float* __restrict__ h2w, const float* __restrict__ h2b,
                        float* __restrict__ hv2){
  __shared__ float s1[32];
  int t = threadIdx.x;
  if (t < 32){
    float a = h1b[t];
    #pragma unroll 8
    for (int i = 0; i < 64; ++i) a += ctx[i]*h1w[t*64+i];
    s1[t] = fmaxf(a, 0.f);
  }
  __syncthreads();
  float a = h2b[t];
  #pragma unroll 8
  for (int i = 0; i < 32; ++i) a += s1[i]*h2w[t*32+i];
  hv2[t] = fmaxf(a, 0.f);
}

// ---------- 3. gw = hv2 @ h3w.T + h3b  ->  Wg_bf (1024x256 bf16), bg (1024 f32) ----------
__global__ void k_gw(const float* __restrict__ hv2,
                     const float* __restrict__ h3w, const float* __restrict__ h3b,
                     unsigned short* __restrict__ Wg_bf, float* __restrict__ bg){
  int t = threadIdx.x;
  int r = blockIdx.x*64 + (t >> 2);
  int q = t & 3;
  const float4* row = (const float4*)(h3w + (size_t)r*64);
  float a = 0.f;
  #pragma unroll
  for (int i = 0; i < 4; ++i){
    float4 v = row[q*4 + i];
    float4 h = *(const float4*)(hv2 + q*16 + i*4);
    a += v.x*h.x + v.y*h.y + v.z*h.z + v.w*h.w;
  }
  a += __shfl_xor(a, 1);
  a += __shfl_xor(a, 2);
  if (q == 0){
    a += h3b[r];
    if (r < WS_)          Wg_bf[r] = f2bf(a);
    else if (r < PER)     bg[r - WS_] = a;
    else if (r < PER+WS_) Wg_bf[WS_ + (r - PER)] = f2bf(a);
    else                  bg[512 + (r - (PER+WS_))] = a;
  }
}

// ---------- 4. gates GEMM: G_T[m(1024)][b(4096)] = sigmoid(Wg[m]·x[b] + bg[m]) ----------
__global__ __launch_bounds__(512, 1)
void k_gates(const unsigned short* __restrict__ Wg_bf,  // 1024 x 256
             const unsigned short* __restrict__ x_bf,   // 4096 x 256
             const float* __restrict__ bg,              // 1024
             float* __restrict__ GT){                    // 1024 x 4096
  __shared__ __align__(16) unsigned short As[128*64];
  __shared__ __align__(16) unsigned short Bs[256*64];
  const int tid  = threadIdx.x;
  const int lane = tid & 63;
  const int wid  = tid >> 6;
  const int wm = wid >> 2, wn = wid & 3;
  const int lrow = lane & 15, lk = lane >> 4;
  const int m0 = blockIdx.x*128;
  const int b0 = blockIdx.y*256;

  f32x4 zero = {0.f,0.f,0.f,0.f};
  f32x4 acc[4][4];
  #pragma unroll
  for (int i=0;i<4;++i)
    #pragma unroll
    for (int j=0;j<4;++j) acc[i][j] = zero;

  for (int kt = 0; kt < 256/64; ++kt){
    __syncthreads();
    #pragma unroll
    for (int i = 0; i < 2; ++i){
      int c = tid + i*512;
      int row = c >> 3, k8 = c & 7;
      uint4 v = *(const uint4*)(Wg_bf + (size_t)(m0+row)*256 + kt*64 + k8*8);
      int idx = (row*64 + k8*8) ^ ((row & 7) << 3);
      *(uint4*)(&As[idx]) = v;
    }
    #pragma unroll
    for (int i = 0; i < 4; ++i){
      int c = tid + i*512;
      int row = c >> 3, k8 = c & 7;
      uint4 v = *(const uint4*)(x_bf + (size_t)(b0+row)*256 + kt*64 + k8*8);
      int idx = (row*64 + k8*8) ^ ((row & 7) << 3);
      *(uint4*)(&Bs[idx]) = v;
    }
    __syncthreads();
    #pragma unroll
    for (int kk = 0; kk < 2; ++kk){
      short8 a[4], b[4];
      #pragma unroll
      for (int fm = 0; fm < 4; ++fm){
        int m = wm*64 + fm*16 + lrow;
        int idx = (m*64 + kk*32 + lk*8) ^ ((m & 7) << 3);
        a[fm] = *(const short8*)(&As[idx]);
      }
      #pragma unroll
      for (int fn = 0; fn < 4; ++fn){
        int r = wn*64 + fn*16 + lrow;
        int idx = (r*64 + kk*32 + lk*8) ^ ((r & 7) << 3);
        b[fn] = *(const short8*)(&Bs[idx]);
      }
      #pragma unroll
      for (int fm = 0; fm < 4; ++fm)
        #pragma unroll
        for (int fn = 0; fn < 4; ++fn)
          acc[fm][fn] = __builtin_amdgcn_mfma_f32_16x16x32_bf16(a[fm], b[fn], acc[fm][fn], 0, 0, 0);
    }
  }
  #pragma unroll
  for (int fm = 0; fm < 4; ++fm){
    float4 bgv = *(const float4*)(bg + m0 + wm*64 + fm*16 + lk*4);
    float bga[4] = {bgv.x, bgv.y, bgv.z, bgv.w};
    #pragma unroll
    for (int reg = 0; reg < 4; ++reg){
      int m = m0 + wm*64 + fm*16 + lk*4 + reg;
      #pragma unroll
      for (int fn = 0; fn < 4; ++fn){
        int b = b0 + wn*64 + fn*16 + lrow;
        float z = acc[fm][fn][reg] + bga[reg];
        GT[(size_t)m*4096 + b] = 1.f/(1.f + __expf(-z));
      }
    }
  }
}

// ---------- 5/6. fused DANN layer (round-3 base + barrier-free epilogue) ----------
// Per-n partial (per wn-wave k-group) goes straight to partg[wn][n][b] in
// global memory: no part LDS, no lgkm drain, no second barrier, no cross-wave
// reduce. k_mid folds partials + bs afterwards.
// Per-iter order: drain(stage gi) -> barrier -> STAGE(gi+1) -> [kt==0: epi
// loads] -> ds_read+MFMA -> [epi: shfl-reduce + 4 float4 stores].
// Staging after the barrier proves the overwritten buffer is no longer read.
// Drain counts (ops younger than stage(gi), deterministic by construction):
//   kt==0: 4 epi-stores -> vmcnt(4); kt==1: 12 epi-loads -> vmcnt(12);
//   else 0 -> vmcnt(0); first iter vmcnt(0) (drains prologue).
template<int KIN, int LAYER>
__global__ __launch_bounds__(512, 1)
void k_layer(const unsigned short* __restrict__ Abf,  // (4096, KIN) bf16
             const unsigned short* __restrict__ Wbf,  // (32768, KIN) bf16
             const float* __restrict__ bb,            // 32768
             const float* __restrict__ Ws,            // 128*256
             const float* __restrict__ GT,            // 1024 x 4096
             float* __restrict__ partg){              // [4][128][4096] f32
  constexpr int NT = KIN/64;
  __shared__ __align__(16) unsigned short As[NT*8192];   // A: NT tiles 128x64
  __shared__ __align__(16) unsigned short Bs[2][16384];  // B: dbuf 256x64

  const int tid  = threadIdx.x;
  const int lane = tid & 63;
  const int wid  = tid >> 6;
  const int wm = wid >> 2, wn = wid & 3;
  const int lrow = lane & 15, lk = lane >> 4;

  const int id     = blockIdx.x;
  const int nstart = (id & 7) * 16;          // XCD-affine 16-n slice
  const int bbase  = (id >> 3) << 7;         // 32 bgroups * 128

  f32x4 zero = {0.f,0.f,0.f,0.f};
  f32x4 acc[4][4];
  #pragma unroll
  for (int i=0;i<4;++i)
    #pragma unroll
    for (int jj=0;jj<4;++jj) acc[i][jj] = zero;

  auto STAGE_B = [&](int buf, int n, int kt){
    #pragma unroll
    for (int i = 0; i < 4; ++i){
      int c = i*512 + tid;
      int row = c >> 3, kc = c & 7;
      const unsigned short* s = Wbf + (size_t)((n<<8)+row)*KIN + kt*64 + ((kc ^ (row&7))<<3);
      gload16(s, &Bs[buf][(i*512 + wid*64)*8]);
    }
  };

  // prologue: all A K-tiles + B tile gi=0
  #pragma unroll
  for (int kt = 0; kt < NT; ++kt)
    #pragma unroll
    for (int i = 0; i < 2; ++i){
      int c = i*512 + tid;
      int row = c >> 3, kc = c & 7;
      const unsigned short* s = Abf + (size_t)(bbase+row)*KIN + kt*64 + ((kc ^ (row&7))<<3);
      gload16(s, &As[kt*8192 + (i*512 + wid*64)*8]);
    }
  STAGE_B(0, nstart, 0);
  asm volatile("" ::: "memory");

  int buf = 0;
  #pragma unroll 1
  for (int nn = 0; nn < 16; ++nn){
    const int n = nstart + nn;
    float4 gv[4];
    float bbv[4], wsv[4];
    #pragma unroll
    for (int kt = 0; kt < NT; ++kt){
      const bool epi  = (kt == NT-1);
      const bool last = epi && (nn == 15);

      // drain stage(gi); counts per header comment
      if (nn == 0 && kt == 0)      asm volatile("s_waitcnt vmcnt(0)"  ::: "memory");
      else if (kt == 0)            asm volatile("s_waitcnt vmcnt(4)"  ::: "memory");
      else if (kt == 1)            asm volatile("s_waitcnt vmcnt(12)" ::: "memory");
      else                         asm volatile("s_waitcnt vmcnt(0)"  ::: "memory");
      __builtin_amdgcn_s_barrier();            // publish Bs[buf]

      if (!last){                              // prefetch gi+1 (safe: post-barrier)
        int nb = n, nkt = kt + 1;
        if (nkt == NT){ nkt = 0; nb = n + 1; }
        STAGE_B(buf ^ 1, nb, nkt);
      }

      if (kt == 0){                            // 12 VMEM loads, exact count
        const int gidx = LAYER*512 + n*4 + wn; // wn == k
        #pragma unroll
        for (int fm = 0; fm < 4; ++fm)
          gv[fm] = *(const float4*)(GT + (size_t)gidx*4096 + bbase + wm*64 + fm*16 + lk*4);
        #pragma unroll
        for (int fn = 0; fn < 4; ++fn){
          int c = wn*64 + fn*16 + lrow;
          bbv[fn] = bb[n*256 + c];
          wsv[fn] = Ws[n*256 + c];
        }
      }

      #pragma unroll
      for (int kk = 0; kk < 2; ++kk){
        short8 a[4], b[4];
        #pragma unroll
        for (int fm = 0; fm < 4; ++fm){
          int m = wm*64 + fm*16 + lrow;
          int idx = kt*8192 + ((m*64 + kk*32 + lk*8) ^ ((m & 7) << 3));
          a[fm] = *(const short8*)(&As[idx]);
        }
        #pragma unroll
        for (int fn = 0; fn < 4; ++fn){
          int r = wn*64 + fn*16 + lrow;
          int idx = (r*64 + kk*32 + lk*8) ^ ((r & 7) << 3);
          b[fn] = *(const short8*)(&Bs[buf][idx]);
        }
        #pragma unroll
        for (int fm = 0; fm < 4; ++fm)
          #pragma unroll
          for (int fn = 0; fn < 4; ++fn)
            acc[fm][fn] = __builtin_amdgcn_mfma_f32_16x16x32_bf16(a[fm], b[fn], acc[fm][fn], 0, 0, 0);
      }

      if (epi){
        // relu(+bb)*Ws, gate, 16-lane shuffle reduce, 4x float4 store. No sync.
        #pragma unroll
        for (int fm = 0; fm < 4; ++fm){
          float gr[4] = {gv[fm].x, gv[fm].y, gv[fm].z, gv[fm].w};
          float sums[4];
          #pragma unroll
          for (int reg = 0; reg < 4; ++reg){
            float s = 0.f;
            #pragma unroll
            for (int fn = 0; fn < 4; ++fn)
              s += fmaxf(acc[fm][fn][reg] + bbv[fn], 0.f) * wsv[fn];
            s *= gr[reg];
            s += __shfl_xor(s, 1);
            s += __shfl_xor(s, 2);
            s += __shfl_xor(s, 4);
            s += __shfl_xor(s, 8);
            sums[reg] = s;
          }
          if (lrow == 0){
            float4 o; o.x = sums[0]; o.y = sums[1]; o.z = sums[2]; o.w = sums[3];
            *(float4*)(partg + (size_t)wn*524288 + (size_t)n*4096
                       + bbase + wm*64 + fm*16 + lk*4) = o;
          }
        }
        #pragma unroll
        for (int i2 = 0; i2 < 4; ++i2)
          #pragma unroll
          for (int j2 = 0; j2 < 4; ++j2) acc[i2][j2] = zero;
      }
      buf ^= 1;
    }
  }
}

// ---------- 6.5 partial fold: out[b][n] = sum_wn partg[wn][n][b] + bs[n] ----------
template<int OUT_BF>
__global__ void k_mid(const float* __restrict__ partg, const float* __restrict__ bsv,
                      unsigned short* __restrict__ obf, float* __restrict__ of32){
  const int n = blockIdx.x;          // 128
  const int t = threadIdx.x;         // 256 threads x 16 b each
  const float* p = partg + (size_t)n*4096 + t*16;
  const float bsn = bsv[n];
  #pragma unroll
  for (int i = 0; i < 4; ++i){
    float4 s0 = *(const float4*)(p + i*4);
    float4 s1 = *(const float4*)(p + 524288 + i*4);
    float4 s2 = *(const float4*)(p + 2*524288 + i*4);
    float4 s3 = *(const float4*)(p + 3*524288 + i*4);
    float v0 = ((s0.x + s1.x) + s2.x) + s3.x + bsn;
    float v1 = ((s0.y + s1.y) + s2.y) + s3.y + bsn;
    float v2 = ((s0.z + s1.z) + s2.z) + s3.z + bsn;
    float v3 = ((s0.w + s1.w) + s2.w) + s3.w + bsn;
    size_t b = (size_t)t*16 + i*4;
    if (OUT_BF){
      obf[(b+0)*128 + n] = f2bf(v0);
      obf[(b+1)*128 + n] = f2bf(v1);
      obf[(b+2)*128 + n] = f2bf(v2);
      obf[(b+3)*128 + n] = f2bf(v3);
    } else {
      of32[(b+0)*128 + n] = v0;
      of32[(b+1)*128 + n] = v1;
      of32[(b+2)*128 + n] = v2;
      of32[(b+3)*128 + n] = v3;
    }
  }
}

// ---------- 7. final projection: out = cur1 @ Wout.T + bout ----------
__global__ void k_final(const float* __restrict__ out1, const float* __restrict__ Wout,
                        const float* __restrict__ bout, float* __restrict__ out){
  int t = blockIdx.x*256 + threadIdx.x;
  int b = t >> 7, o = t & 127;
  const float4* cr = (const float4*)(out1 + (size_t)b*128);
  const float4* wr = (const float4*)(Wout + (size_t)o*128);
  float a = 0.f;
  #pragma unroll
  for (int i = 0; i < 32; ++i){
    float4 c = cr[i], w = wr[i];
    a += c.x*w.x + c.y*w.y + c.z*w.z + c.w*w.w;
  }
  out[t] = a + bout[o];
}

// ---------- launch ----------
extern "C" void kernel_launch(void* const* d_in, const int* in_sizes, int n_in,
                              void* d_out, int out_size, void* d_ws, size_t ws_size,
                              hipStream_t stream){
  const float* x    = (const float*)d_in[0];
  const float* ctx  = (const float*)d_in[1];
  const float* Wb0  = (const float*)d_in[2];
  const float* bb0  = (const float*)d_in[3];
  const float* Ws0  = (const float*)d_in[4];
  const float* bs0  = (const float*)d_in[5];
  const float* Wb1  = (const float*)d_in[6];
  const float* bb1  = (const float*)d_in[7];
  const float* Ws1  = (const float*)d_in[8];
  const float* bs1  = (const float*)d_in[9];
  const float* Wout = (const float*)d_in[10];
  const float* bout = (const float*)d_in[11];
  const float* h1w  = (const float*)d_in[12];
  const float* h1b  = (const float*)d_in[13];
  const float* h2w  = (const float*)d_in[14];
  const float* h2b  = (const float*)d_in[15];
  const float* h3w  = (const float*)d_in[16];
  const float* h3b  = (const float*)d_in[17];
  float* out = (float*)d_out;

  char* ws = (char*)d_ws;
  size_t o = 0;
  unsigned short* x_bf  = (unsigned short*)(ws + o); o += (size_t)4096*256*2;
  unsigned short* W0b   = (unsigned short*)(ws + o); o += (size_t)8388608*2;
  unsigned short* W1b   = (unsigned short*)(ws + o); o += (size_t)4194304*2;
  unsigned short* Wg_bf = (unsigned short*)(ws + o); o += (size_t)1024*256*2;
  float* bg   = (float*)(ws + o); o += 1024*4;
  float* hv2  = (float*)(ws + o); o += 256;
  float* GT   = (float*)(ws + o); o += (size_t)1024*4096*4;
  unsigned short* cur_bf = (unsigned short*)(ws + o); o += (size_t)4096*128*2;
  float* out1 = (float*)(ws + o); o += (size_t)4096*128*4;
  float* partg0 = (float*)(ws + o); o += (size_t)4*128*4096*4;   // 8 MB
  float* partg1 = (float*)W0b;      // alias: W0b dead after k_layer0

  k_convert<<<13312, 256, 0, stream>>>(x, Wb0, Wb1, x_bf, W0b, W1b);
  k_hyper<<<1, 64, 0, stream>>>(ctx, h1w, h1b, h2w, h2b, hv2);
  k_gw<<<4112, 256, 0, stream>>>(hv2, h3w, h3b, Wg_bf, bg);
  k_gates<<<dim3(8, 16), 512, 0, stream>>>(Wg_bf, x_bf, bg, GT);
  k_layer<256, 0><<<256, 512, 0, stream>>>(x_bf, W0b, bb0, Ws0, GT, partg0);
  k_mid<1><<<128, 256, 0, stream>>>(partg0, bs0, cur_bf, nullptr);
  k_layer<128, 1><<<256, 512, 0, stream>>>(cur_bf, W1b, bb1, Ws1, GT, partg1);
  k_mid<0><<<128, 256, 0, stream>>>(partg1, bs1, nullptr, out1);
  k_final<<<2048, 256, 0, stream>>>(out1, Wout, bout, out);
}